// Round 4
// baseline (183.613 us; speedup 1.0000x reference)
//
#include <hip/hip_runtime.h>

#define T_LEN 32768
#define ADIM  512
#define NDEC  1024
#define KTAPS 31

// workspace float offsets (no aliasing — ws is huge)
#define WS_BASE 0        // 512   : dec_proj[a] + conv-bias proj        (k0->k1)
#define WS_G    512      // 8192 floats = 32KB: G as bf16 MFMA B-fragments (k0->k1)
#define WS_SARR 16384    // 32768 : sv[t] = 2*(e[t]+mask[t])            (k1->k3)
#define WS_BMAX 49152    // 2048  : per-k1-block online max   (2048 k1 blocks)
#define WS_BSUM 51200    // 2048  : per-k1-block online sumexp
#define WS_SSUM 53248    // 1     : S = sum of clipped u                (k3->k4)
#define WS_U    53504    // 32768 : unnormalized u[t]                   (k3->k4)
#define WS_CREP 86272    // 16384 : 32 replicated c~ accumulators (zeroed by k1 blocks 0..31)

typedef __attribute__((ext_vector_type(8))) short bf16x8;
typedef __attribute__((ext_vector_type(4))) float f32x4;

__device__ __forceinline__ float fast_tanh(float x) {
    // tanh(x) = 1 - 2/(exp(2x)+1); ~1e-7 abs err vs 3.5e-4 threshold
    float e = __expf(2.0f * x);
    return 1.0f - 2.0f * __builtin_amdgcn_rcpf(e + 1.0f);
}

__device__ __forceinline__ unsigned short f2bf(float f) {
    // f32 -> bf16 round-to-nearest-even
    unsigned u = __float_as_uint(f);
    return (unsigned short)((u + 0x7FFFu + ((u >> 16) & 1u)) >> 16);
}

// ---------------- K0: dec_proj+bias -> base[512]; G B-fragments (bf16); zero SSUM -----
// G-fragment layout for mfma_f32_16x16x32_bf16 B-operand: per a-tile `at` (16 a's),
// lane l holds B[k][col] for col = l&15, k = 8*(l>>4)+i (i=0..7 contiguous bf16).
// Stored at u16 index (at*64 + l)*8 + i. k=31 is the zero pad tap (K=32).
__global__ __launch_bounds__(256) void k0_prep(
        const float* __restrict__ dec_z, const float* __restrict__ conv_w,
        const float* __restrict__ conv_b, const float* __restrict__ W_att,
        const float* __restrict__ W_dec, float* __restrict__ ws) {
    int b = blockIdx.x, tid = threadIdx.x;
    int lane = tid & 63, wave = tid >> 6;
    if (b < 64) {
        if (b == 0 && tid == 0) ws[WS_SSUM] = 0.f;
        // 8 a's per block, wave handles 2 (64-lane dot over 1024)
        for (int s = 0; s < 2; ++s) {
            int a = b * 8 + wave * 2 + s;
            float sum = 0.f;
            #pragma unroll
            for (int i = 0; i < 16; ++i)
                sum += W_dec[a * NDEC + i * 64 + lane] * dec_z[i * 64 + lane];
            #pragma unroll
            for (int off = 32; off > 0; off >>= 1) sum += __shfl_xor(sum, off);
            if (lane == 0) {
                float bias = 0.f;
                #pragma unroll
                for (int c = 0; c < 32; ++c) bias += conv_b[c] * W_att[a * 32 + c];
                ws[WS_BASE + a] = sum + bias;
            }
        }
    } else {
        int k = b - 64;                 // 0..31 (31 = zero pad)
        unsigned short* Gf = (unsigned short*)(ws + WS_G);
        for (int s = 0; s < 2; ++s) {
            int a = 2 * tid + s;
            float g = 0.f;
            if (k < KTAPS) {
                #pragma unroll
                for (int c = 0; c < 32; ++c)
                    g += conv_w[c * KTAPS + k] * W_att[a * 32 + c];
            }
            int at = a >> 4, col = a & 15;
            int l = col | ((k >> 3) << 4), i = k & 7;
            Gf[(at * 64 + l) * 8 + i] = f2bf(g);
        }
    }
}

// ---------------- K1 v3: DMA-staged pre + MFMA conv + tanh-dot energies --------------
// DIAGNOSIS (R0-R2): three different k1 structures (VALU-heavy/occupancy-2x/MFMA) all
// ran 40-44 us = 1.6 TB/s effective read of the 64 MB `pre` stream — register-load
// miss-tracking limited. FIX: stage pre via __builtin_amdgcn_global_load_lds
// (VGPR-free, deep vmcnt queue — m97-proven read path). 2048 blocks x 512 thr;
// block = 16 t x 512 a; LDS tile 32 KB. 8 waves: wave stages rows {2w,2w+1}
// (4 x 1KB DMAs), then owns a-octant wave*64 (4 MFMA a-tiles).
// (512,8): 64-VGPR cap (live set ~40, no spill) -> 4 blocks/CU resident, LDS 132 KB.
__global__ __launch_bounds__(512, 8) void k1_energy(
        const float* __restrict__ att_prev, const float* __restrict__ pre,
        const float* __restrict__ mask, const float* __restrict__ W_g,
        const float* __restrict__ b_g, float* __restrict__ ws) {
    __shared__ float pre_s[16 * ADIM];   // 32 KB
    __shared__ float ap_s[48];
    __shared__ float eP[8][16];
    int tid = threadIdx.x, lane = tid & 63, wave = tid >> 6;
    int t0 = blockIdx.x * 16;

    // zero c~ replicas for k3 (kernel boundary = the fence; NO __threadfence here —
    // R6's per-block device fence cost 115 us in k3)
    if (blockIdx.x < 32) ws[WS_CREP + blockIdx.x * 512 + tid] = 0.f;

    // async-stage the 16x512 pre tile: wave w -> rows {2w, 2w+1}, 2 half-rows each.
    // global src is per-lane (base + lane*16B); LDS dest is wave-uniform (HW adds
    // lane*16). 4 outstanding 1KB DMAs per wave, zero VGPR cost.
    {
        const float* grow = pre + (size_t)(t0 + 2 * wave) * ADIM + lane * 4;
        float* lrow = &pre_s[(2 * wave) * ADIM];
        #pragma unroll
        for (int r = 0; r < 2; ++r) {
            #pragma unroll
            for (int h = 0; h < 2; ++h) {
                __builtin_amdgcn_global_load_lds(
                    (const __attribute__((address_space(1))) void*)(grow + r * ADIM + h * 256),
                    (__attribute__((address_space(3))) void*)(lrow + r * ADIM + h * 256),
                    16, 0, 0);
            }
        }
    }
    if (tid < 48) {
        int g = t0 - 15 + tid;
        ap_s[tid] = (g >= 0 && g < T_LEN) ? att_prev[g] : 0.f;
    }
    __syncthreads();   // compiler emits vmcnt(0)+lgkmcnt(0) drain before barrier

    int row = lane & 15, g4 = lane >> 4;

    // A fragment (R2-verified layout): A[t][k] = ap_s[t + k]; lane: t=row, k=8*g4+i
    bf16x8 afrag;
    int aidx = row + g4 * 8;
    #pragma unroll
    for (int i = 0; i < 8; ++i) afrag[i] = (short)f2bf(ap_s[aidx + i]);

    const unsigned short* Gf = (const unsigned short*)(ws + WS_G);
    float e_acc[4] = {0.f, 0.f, 0.f, 0.f};

    #pragma unroll 2
    for (int p = 0; p < 4; ++p) {
        int at = wave * 4 + p;
        int ac = at * 16 + row;                                   // this lane's a
        bf16x8 bfrag = *(const bf16x8*)(Gf + (size_t)(at * 64 + lane) * 8);
        float bs = ws[WS_BASE + ac];
        f32x4 c = {bs, bs, bs, bs};
        c = __builtin_amdgcn_mfma_f32_16x16x32_bf16(afrag, bfrag, c, 0, 0, 0);
        float wgv = W_g[ac];
        // D layout (m89-verified): col=lane&15 (=a), row=(lane>>4)*4+r (=t)
        #pragma unroll
        for (int r = 0; r < 4; ++r) {
            float pv = pre_s[(g4 * 4 + r) * ADIM + ac];
            e_acc[r] = fmaf(fast_tanh(c[r] + pv), wgv, e_acc[r]);
        }
    }

    // sum over the 16 a-columns within each lane group
    #pragma unroll
    for (int r = 0; r < 4; ++r) {
        float s = e_acc[r];
        s += __shfl_xor(s, 1); s += __shfl_xor(s, 2);
        s += __shfl_xor(s, 4); s += __shfl_xor(s, 8);
        e_acc[r] = s;
    }
    if (row == 0) {
        #pragma unroll
        for (int r = 0; r < 4; ++r) eP[wave][g4 * 4 + r] = e_acc[r];
    }
    __syncthreads();

    // wave 0: combine 8 a-octants, write sv, masked 64-lane online (M,Z) butterfly
    if (wave == 0) {
        float sv = -1e30f, z0 = 0.f;
        if (lane < 16) {
            float e = 0.f;
            #pragma unroll
            for (int q = 0; q < 8; ++q) e += eP[q][lane];
            int t = t0 + lane;
            sv = 2.0f * (e + b_g[0] + mask[t]);
            ws[WS_SARR + t] = sv;
            z0 = 1.0f;
        }
        float m = sv, z = z0;
        #pragma unroll
        for (int off = 32; off > 0; off >>= 1) {
            float mo = __shfl_xor(m, off), zo = __shfl_xor(z, off);
            float mn = fmaxf(m, mo);
            z = z * __expf(m - mn) + zo * __expf(mo - mn);
            m = mn;
        }
        if (lane == 0) { ws[WS_BMAX + blockIdx.x] = m; ws[WS_BSUM + blockIdx.x] = z; }
    }
}

// ---------------- K3 v2: DMA-staged enc_h + barrier-free (M,Z) + LDS context sum -----
// R3 diagnosis: k3 (~38 us) was the last register-float4 streaming kernel — the exact
// path proven slow in k1. Now: 1024 blocks x 512 thr; block = 32 t x 512 a; enc_h tile
// DMA-staged into 64 KB LDS (16 x 1KB DMAs per wave, issued FIRST). While the DMAs fly:
// per-wave REDUNDANT (M,Z) combine (32 serial online combines/lane over the 2048 pairs
// + 64-lane butterfly — no cross-wave barrier, so no early vmcnt(0) drain), then lanes
// 0..31 compute u[t] in-register. ONE __syncthreads (the DMA drain), then wave w
// accumulates a = 64w+lane over 32 t's from LDS with u broadcast via __shfl; one
// atomicAdd per thread into replica (blockIdx & 31). cbuf/team structure removed.
__global__ __launch_bounds__(512) void k3_context(
        const float* __restrict__ att_prev, const float* __restrict__ enc_h,
        float* __restrict__ ws) {
    __shared__ float enc_s[32 * ADIM];   // 64 KB (exactly the static cap)
    int tid = threadIdx.x, lane = tid & 63, wave = tid >> 6;
    int t0 = blockIdx.x * 32;

    // 1) issue the 32x512 f32 tile DMAs: wave w -> rows 4w..4w+3, 2 halves each
    {
        const float* grow = enc_h + (size_t)(t0 + 4 * wave) * ADIM + lane * 4;
        float* lrow = &enc_s[(4 * wave) * ADIM];
        #pragma unroll
        for (int r = 0; r < 4; ++r) {
            #pragma unroll
            for (int h = 0; h < 2; ++h) {
                __builtin_amdgcn_global_load_lds(
                    (const __attribute__((address_space(1))) void*)(grow + r * ADIM + h * 256),
                    (__attribute__((address_space(3))) void*)(lrow + r * ADIM + h * 256),
                    16, 0, 0);
            }
        }
    }

    // 2) per-wave redundant combine of the 2048 (M,Z) pairs (hides under DMA flight)
    float m = -1e30f, z = 0.f;
    #pragma unroll 8
    for (int q = 0; q < 32; ++q) {
        float mo = ws[WS_BMAX + q * 64 + lane];
        float zo = ws[WS_BSUM + q * 64 + lane];
        float mn = fmaxf(m, mo);
        z = z * __expf(m - mn) + zo * __expf(mo - mn);
        m = mn;
    }
    #pragma unroll
    for (int off = 32; off > 0; off >>= 1) {
        float mo = __shfl_xor(m, off), zo = __shfl_xor(z, off);
        float mn = fmaxf(m, mo);
        z = z * __expf(m - mn) + zo * __expf(mo - mn);
        m = mn;
    }
    float invZ = 1.0f / z;

    // 3) lanes 0..31 of EVERY wave: u[t] in-register (each wave needs it for shfl)
    float u = 0.f;
    if (lane < 32) {
        int t = t0 + lane;
        float ap0 = att_prev[t];
        float apm = (t > 0) ? att_prev[t - 1] : 0.f;
        u = fmaxf((ap0 + apm) * __expf(ws[WS_SARR + t] - m) * invZ, 1e-6f);
    }
    // wave 0 additionally persists u[t] and the S partial
    if (wave == 0) {
        if (lane < 32) ws[WS_U + t0 + lane] = u;
        float s = (lane < 32) ? u : 0.f;
        #pragma unroll
        for (int off = 16; off > 0; off >>= 1) s += __shfl_xor(s, off, 32);
        if (lane == 0) atomicAdd(&ws[WS_SSUM], s);
    }

    __syncthreads();   // single drain: DMAs have had the whole combine to land

    // 4) context accumulate: wave w owns a = 64w + lane
    int a = wave * 64 + lane;
    float acc = 0.f;
    #pragma unroll
    for (int t = 0; t < 32; ++t)
        acc = fmaf(__shfl(u, t), enc_s[t * ADIM + a], acc);
    atomicAdd(&ws[WS_CREP + (blockIdx.x & 31) * 512 + a], acc);
}

// ---------------- K4: c = (sum replicas)/S -> out[0:512]; w = u/S -> out[512:] --------
__global__ __launch_bounds__(512) void k4_final(
        const float* __restrict__ ws, float* __restrict__ out) {
    int b = blockIdx.x, tid = threadIdx.x;
    float invS = 1.0f / ws[WS_SSUM];
    if (b == 0) {
        float acc = 0.f;
        #pragma unroll
        for (int r = 0; r < 32; ++r) acc += ws[WS_CREP + r * 512 + tid];
        out[tid] = acc * invS;
    } else {
        int i = (b - 1) * 512 + tid;
        out[512 + i] = ws[WS_U + i] * invS;
    }
}

extern "C" void kernel_launch(void* const* d_in, const int* in_sizes, int n_in,
                              void* d_out, int out_size, void* d_ws, size_t ws_size,
                              hipStream_t stream) {
    const float* dec_z    = (const float*)d_in[0];
    const float* att_prev = (const float*)d_in[1];
    const float* pre      = (const float*)d_in[2];
    const float* enc_h    = (const float*)d_in[3];
    const float* mask     = (const float*)d_in[4];
    const float* conv_w   = (const float*)d_in[5];
    const float* conv_b   = (const float*)d_in[6];
    const float* W_att    = (const float*)d_in[7];
    const float* W_dec    = (const float*)d_in[8];
    const float* W_g      = (const float*)d_in[9];
    const float* b_g      = (const float*)d_in[10];
    float* out = (float*)d_out;
    float* ws  = (float*)d_ws;

    k0_prep   <<<96,   256, 0, stream>>>(dec_z, conv_w, conv_b, W_att, W_dec, ws);
    k1_energy <<<2048, 512, 0, stream>>>(att_prev, pre, mask, W_g, b_g, ws);
    k3_context<<<1024, 512, 0, stream>>>(att_prev, enc_h, ws);
    k4_final  <<<65,   512, 0, stream>>>(ws, out);
}

// Round 5
// 181.801 us; speedup vs baseline: 1.0100x; 1.0100x over previous
//
#include <hip/hip_runtime.h>

#define T_LEN 32768
#define ADIM  512
#define NDEC  1024
#define KTAPS 31

// workspace float offsets (no aliasing — ws is huge)
#define WS_BASE 0        // 512   : dec_proj[a] + conv-bias proj        (k0->k1)
#define WS_G    512      // 8192 floats = 32KB: G as bf16 MFMA B-fragments (k0->k1)
#define WS_SARR 16384    // 32768 : sv[t] = 2*(e[t]+mask[t])            (k1->k3)
#define WS_BMAX 49152    // 2048  : per-k1-block online max   (2048 k1 blocks)
#define WS_BSUM 51200    // 2048  : per-k1-block online sumexp
#define WS_SSUM 53248    // 1     : S = sum of clipped u                (k3->k4)
#define WS_U    53504    // 32768 : unnormalized u[t]                   (k3->k4)
#define WS_CREP 86272    // 16384 : 32 replicated c~ accumulators (zeroed by k1 blocks 0..31)

typedef __attribute__((ext_vector_type(8))) short bf16x8;
typedef __attribute__((ext_vector_type(4))) float f32x4;

__device__ __forceinline__ float fast_tanh(float x) {
    // tanh(x) = 1 - 2/(exp(2x)+1); ~1e-7 abs err vs 3.5e-4 threshold
    float e = __expf(2.0f * x);
    return 1.0f - 2.0f * __builtin_amdgcn_rcpf(e + 1.0f);
}

__device__ __forceinline__ unsigned short f2bf(float f) {
    // f32 -> bf16 round-to-nearest-even
    unsigned u = __float_as_uint(f);
    return (unsigned short)((u + 0x7FFFu + ((u >> 16) & 1u)) >> 16);
}

// ---------------- K0: dec_proj+bias -> base[512]; G B-fragments (bf16); zero SSUM -----
// G-fragment layout for mfma_f32_16x16x32_bf16 B-operand: per a-tile `at` (16 a's),
// lane l holds B[k][col] for col = l&15, k = 8*(l>>4)+i (i=0..7 contiguous bf16).
// Stored at u16 index (at*64 + l)*8 + i. k=31 is the zero pad tap (K=32).
__global__ __launch_bounds__(256) void k0_prep(
        const float* __restrict__ dec_z, const float* __restrict__ conv_w,
        const float* __restrict__ conv_b, const float* __restrict__ W_att,
        const float* __restrict__ W_dec, float* __restrict__ ws) {
    int b = blockIdx.x, tid = threadIdx.x;
    int lane = tid & 63, wave = tid >> 6;
    if (b < 64) {
        if (b == 0 && tid == 0) ws[WS_SSUM] = 0.f;
        // 8 a's per block, wave handles 2 (64-lane dot over 1024)
        for (int s = 0; s < 2; ++s) {
            int a = b * 8 + wave * 2 + s;
            float sum = 0.f;
            #pragma unroll
            for (int i = 0; i < 16; ++i)
                sum += W_dec[a * NDEC + i * 64 + lane] * dec_z[i * 64 + lane];
            #pragma unroll
            for (int off = 32; off > 0; off >>= 1) sum += __shfl_xor(sum, off);
            if (lane == 0) {
                float bias = 0.f;
                #pragma unroll
                for (int c = 0; c < 32; ++c) bias += conv_b[c] * W_att[a * 32 + c];
                ws[WS_BASE + a] = sum + bias;
            }
        }
    } else {
        int k = b - 64;                 // 0..31 (31 = zero pad)
        unsigned short* Gf = (unsigned short*)(ws + WS_G);
        for (int s = 0; s < 2; ++s) {
            int a = 2 * tid + s;
            float g = 0.f;
            if (k < KTAPS) {
                #pragma unroll
                for (int c = 0; c < 32; ++c)
                    g += conv_w[c * KTAPS + k] * W_att[a * 32 + c];
            }
            int at = a >> 4, col = a & 15;
            int l = col | ((k >> 3) << 4), i = k & 7;
            Gf[(at * 64 + l) * 8 + i] = f2bf(g);
        }
    }
}

// ---------------- K1 v3: DMA-staged pre + MFMA conv + tanh-dot energies --------------
// (unchanged from R3/R4 — the only k1 structure that produced measured gains.)
// 2048 blocks x 512 thr; block = 16 t x 512 a; 32 KB LDS tile via global_load_lds;
// 8 waves: wave stages rows {2w,2w+1}, then owns a-octant wave*64 (4 MFMA a-tiles).
__global__ __launch_bounds__(512, 8) void k1_energy(
        const float* __restrict__ att_prev, const float* __restrict__ pre,
        const float* __restrict__ mask, const float* __restrict__ W_g,
        const float* __restrict__ b_g, float* __restrict__ ws) {
    __shared__ float pre_s[16 * ADIM];   // 32 KB
    __shared__ float ap_s[48];
    __shared__ float eP[8][16];
    int tid = threadIdx.x, lane = tid & 63, wave = tid >> 6;
    int t0 = blockIdx.x * 16;

    // zero c~ replicas for k3 (kernel boundary = the fence)
    if (blockIdx.x < 32) ws[WS_CREP + blockIdx.x * 512 + tid] = 0.f;

    {
        const float* grow = pre + (size_t)(t0 + 2 * wave) * ADIM + lane * 4;
        float* lrow = &pre_s[(2 * wave) * ADIM];
        #pragma unroll
        for (int r = 0; r < 2; ++r) {
            #pragma unroll
            for (int h = 0; h < 2; ++h) {
                __builtin_amdgcn_global_load_lds(
                    (const __attribute__((address_space(1))) void*)(grow + r * ADIM + h * 256),
                    (__attribute__((address_space(3))) void*)(lrow + r * ADIM + h * 256),
                    16, 0, 0);
            }
        }
    }
    if (tid < 48) {
        int g = t0 - 15 + tid;
        ap_s[tid] = (g >= 0 && g < T_LEN) ? att_prev[g] : 0.f;
    }
    __syncthreads();   // vmcnt(0)+lgkmcnt(0) drain

    int row = lane & 15, g4 = lane >> 4;

    // A fragment (R2-verified layout): A[t][k] = ap_s[t + k]; lane: t=row, k=8*g4+i
    bf16x8 afrag;
    int aidx = row + g4 * 8;
    #pragma unroll
    for (int i = 0; i < 8; ++i) afrag[i] = (short)f2bf(ap_s[aidx + i]);

    const unsigned short* Gf = (const unsigned short*)(ws + WS_G);
    float e_acc[4] = {0.f, 0.f, 0.f, 0.f};

    #pragma unroll 2
    for (int p = 0; p < 4; ++p) {
        int at = wave * 4 + p;
        int ac = at * 16 + row;
        bf16x8 bfrag = *(const bf16x8*)(Gf + (size_t)(at * 64 + lane) * 8);
        float bs = ws[WS_BASE + ac];
        f32x4 c = {bs, bs, bs, bs};
        c = __builtin_amdgcn_mfma_f32_16x16x32_bf16(afrag, bfrag, c, 0, 0, 0);
        float wgv = W_g[ac];
        // D layout (m89-verified): col=lane&15 (=a), row=(lane>>4)*4+r (=t)
        #pragma unroll
        for (int r = 0; r < 4; ++r) {
            float pv = pre_s[(g4 * 4 + r) * ADIM + ac];
            e_acc[r] = fmaf(fast_tanh(c[r] + pv), wgv, e_acc[r]);
        }
    }

    #pragma unroll
    for (int r = 0; r < 4; ++r) {
        float s = e_acc[r];
        s += __shfl_xor(s, 1); s += __shfl_xor(s, 2);
        s += __shfl_xor(s, 4); s += __shfl_xor(s, 8);
        e_acc[r] = s;
    }
    if (row == 0) {
        #pragma unroll
        for (int r = 0; r < 4; ++r) eP[wave][g4 * 4 + r] = e_acc[r];
    }
    __syncthreads();

    if (wave == 0) {
        float sv = -1e30f, z0 = 0.f;
        if (lane < 16) {
            float e = 0.f;
            #pragma unroll
            for (int q = 0; q < 8; ++q) e += eP[q][lane];
            int t = t0 + lane;
            sv = 2.0f * (e + b_g[0] + mask[t]);
            ws[WS_SARR + t] = sv;
            z0 = 1.0f;
        }
        float m = sv, z = z0;
        #pragma unroll
        for (int off = 32; off > 0; off >>= 1) {
            float mo = __shfl_xor(m, off), zo = __shfl_xor(z, off);
            float mn = fmaxf(m, mo);
            z = z * __expf(m - mn) + zo * __expf(mo - mn);
            m = mn;
        }
        if (lane == 0) { ws[WS_BMAX + blockIdx.x] = m; ws[WS_BSUM + blockIdx.x] = z; }
    }
}

// ---------------- K3 v3: LN-shaped streaming context (no staging, no drain) ----------
// R4 POST-MORTEM: v1 (reg-tile+teams) and v2 (DMA+64KB LDS+vmcnt drain) are
// time-identical -> neither matched the m219 LN shape that hits 82% HBM BW:
// grid-stride register streaming, no LDS staging, no barrier in the load stream,
// all blocks co-resident, loads hoisted 8-deep. This version IS that shape:
// 512 blocks x 512 thr (all co-resident, 16 waves/CU), thread owns 4 a-cols over
// 64 t's (two 32-t tiles). Per tile: compute the 8 u's FIRST (hot 128KB arrays),
// THEN 8 independent float4 enc loads (statically-indexed e[8] regs), THEN fma.
// (M,Z) prologue: 8 hoisted independent loads/lane, no dependent-load chain.
// One replica-atomic set per block (halved vs before). LDS = 8KB cbuf only.
__global__ __launch_bounds__(512, 4) void k3_context(
        const float* __restrict__ att_prev, const float* __restrict__ enc_h,
        float* __restrict__ ws) {
    __shared__ float wmz[16];
    __shared__ float cbuf[4 * 512];
    int tid = threadIdx.x, lane = tid & 63, wave = tid >> 6;

    // 1) combine 2048 (M,Z): lane l of wave w loads pairs q = w+8k (8 indep loads)
    float mo[4], zo[4];
    #pragma unroll
    for (int k = 0; k < 4; ++k) {
        mo[k] = ws[WS_BMAX + (wave + 8 * k) * 64 + lane];
        zo[k] = ws[WS_BSUM + (wave + 8 * k) * 64 + lane];
    }
    float m = mo[0], z = zo[0];
    #pragma unroll
    for (int k = 1; k < 4; ++k) {
        float mn = fmaxf(m, mo[k]);
        z = z * __expf(m - mn) + zo[k] * __expf(mo[k] - mn);
        m = mn;
    }
    #pragma unroll
    for (int off = 32; off > 0; off >>= 1) {
        float mx = __shfl_xor(m, off), zx = __shfl_xor(z, off);
        float mn = fmaxf(m, mx);
        z = z * __expf(m - mn) + zx * __expf(mx - mn);
        m = mn;
    }
    if (lane == 0) { wmz[wave] = m; wmz[8 + wave] = z; }
    __syncthreads();
    float M = wmz[0], Z = wmz[8];
    #pragma unroll
    for (int w = 1; w < 8; ++w) {
        float mn = fmaxf(M, wmz[w]);
        Z = Z * __expf(M - mn) + wmz[8 + w] * __expf(wmz[w] - mn);
        M = mn;
    }
    float invZ = 1.0f / Z;

    int team = tid >> 7, l = tid & 127;
    int a4 = 4 * l;
    float4 acc = make_float4(0.f, 0.f, 0.f, 0.f);

    #pragma unroll 1
    for (int half = 0; half < 2; ++half) {
        int t0 = blockIdx.x * 64 + half * 32;
        int tb = t0 + team * 8;

        // u first (sv/att_prev are 128KB L2/L3-hot; broadcast across team)
        float u[8];
        #pragma unroll
        for (int i = 0; i < 8; ++i) {
            int t = tb + i;
            float ap0 = att_prev[t];
            float apm = (t > 0) ? att_prev[t - 1] : 0.f;
            u[i] = fmaxf((ap0 + apm) * __expf(ws[WS_SARR + t] - M) * invZ, 1e-6f);
        }
        // 8 independent vector loads in flight, statically indexed (rule #20)
        float4 e[8];
        #pragma unroll
        for (int i = 0; i < 8; ++i)
            e[i] = *(const float4*)(enc_h + (size_t)(tb + i) * ADIM + a4);
        #pragma unroll
        for (int i = 0; i < 8; ++i) {
            acc.x = fmaf(u[i], e[i].x, acc.x);
            acc.y = fmaf(u[i], e[i].y, acc.y);
            acc.z = fmaf(u[i], e[i].z, acc.z);
            acc.w = fmaf(u[i], e[i].w, acc.w);
        }

        // wave 0, lanes 0..31: persist u[t] + S partial for this 32-t tile
        if (wave == 0 && lane < 32) {
            int t = t0 + lane;
            float ap0 = att_prev[t];
            float apm = (t > 0) ? att_prev[t - 1] : 0.f;
            float uu = fmaxf((ap0 + apm) * __expf(ws[WS_SARR + t] - M) * invZ, 1e-6f);
            ws[WS_U + t] = uu;
            float s = uu;
            #pragma unroll
            for (int off = 16; off > 0; off >>= 1) s += __shfl_xor(s, off, 32);
            if (lane == 0) atomicAdd(&ws[WS_SSUM], s);
        }
    }

    // cross-team reduce + one replica-atomic set per block
    if (team != 0) *(float4*)&cbuf[team * 512 + a4] = acc;
    __syncthreads();
    if (team == 0) {
        float4 b1 = *(const float4*)&cbuf[1 * 512 + a4];
        float4 b2 = *(const float4*)&cbuf[2 * 512 + a4];
        float4 b3 = *(const float4*)&cbuf[3 * 512 + a4];
        float* rep = ws + WS_CREP + (blockIdx.x & 31) * 512;
        atomicAdd(&rep[a4 + 0], acc.x + b1.x + b2.x + b3.x);
        atomicAdd(&rep[a4 + 1], acc.y + b1.y + b2.y + b3.y);
        atomicAdd(&rep[a4 + 2], acc.z + b1.z + b2.z + b3.z);
        atomicAdd(&rep[a4 + 3], acc.w + b1.w + b2.w + b3.w);
    }
}

// ---------------- K4: c = (sum replicas)/S -> out[0:512]; w = u/S -> out[512:] --------
__global__ __launch_bounds__(512) void k4_final(
        const float* __restrict__ ws, float* __restrict__ out) {
    int b = blockIdx.x, tid = threadIdx.x;
    float invS = 1.0f / ws[WS_SSUM];
    if (b == 0) {
        float acc = 0.f;
        #pragma unroll
        for (int r = 0; r < 32; ++r) acc += ws[WS_CREP + r * 512 + tid];
        out[tid] = acc * invS;
    } else {
        int i = (b - 1) * 512 + tid;
        out[512 + i] = ws[WS_U + i] * invS;
    }
}

extern "C" void kernel_launch(void* const* d_in, const int* in_sizes, int n_in,
                              void* d_out, int out_size, void* d_ws, size_t ws_size,
                              hipStream_t stream) {
    const float* dec_z    = (const float*)d_in[0];
    const float* att_prev = (const float*)d_in[1];
    const float* pre      = (const float*)d_in[2];
    const float* enc_h    = (const float*)d_in[3];
    const float* mask     = (const float*)d_in[4];
    const float* conv_w   = (const float*)d_in[5];
    const float* conv_b   = (const float*)d_in[6];
    const float* W_att    = (const float*)d_in[7];
    const float* W_dec    = (const float*)d_in[8];
    const float* W_g      = (const float*)d_in[9];
    const float* b_g      = (const float*)d_in[10];
    float* out = (float*)d_out;
    float* ws  = (float*)d_ws;

    k0_prep   <<<96,   256, 0, stream>>>(dec_z, conv_w, conv_b, W_att, W_dec, ws);
    k1_energy <<<2048, 512, 0, stream>>>(att_prev, pre, mask, W_g, b_g, ws);
    k3_context<<<512,  512, 0, stream>>>(att_prev, enc_h, ws);
    k4_final  <<<65,   512, 0, stream>>>(ws, out);
}